// Round 1
// baseline (156.410 us; speedup 1.0000x reference)
//
#include <hip/hip_runtime.h>
#include <hip/hip_bf16.h>

#define N_OBJ   32
#define G_TOTAL 4960      // C(32,3)
#define N_FILT  16
#define REL_D   16
#define BATCH   32
#define NQ      512

typedef __attribute__((ext_vector_type(8))) short bf16x8;
typedef __attribute__((ext_vector_type(4))) float f32x4;

static __device__ inline unsigned short f2bf(float x) {
    union { float f; unsigned int u; } v; v.f = x;
    unsigned int r = v.u + 0x7fffu + ((v.u >> 16) & 1u);   // RNE
    return (unsigned short)(r >> 16);
}

// ---------------- kernel 0: unrank lexicographic 3-combinations ----------------
__global__ void k_idx(int* __restrict__ idxp) {
    int g = blockIdx.x * 256 + threadIdx.x;
    if (g >= G_TOTAL) return;
    int rem = g, a = 0, b = 0;
    for (a = 0; a < N_OBJ - 2; a++) {
        int cnt = (N_OBJ - 1 - a) * (N_OBJ - 2 - a) / 2;
        if (rem < cnt) break;
        rem -= cnt;
    }
    for (b = a + 1; b < N_OBJ - 1; b++) {
        int cnt = N_OBJ - 1 - b;
        if (rem < cnt) break;
        rem -= cnt;
    }
    int c = b + 1 + rem;
    idxp[g] = a | (b << 8) | (c << 16);
}

// ---------------- kernel A: softplus -> product -> softmax -> bf16 ----------------
__global__ __launch_bounds__(256) void k_normw(const float* __restrict__ logits,
                                               const int* __restrict__ idxp,
                                               unsigned short* __restrict__ normw) {
    __shared__ float sp[N_OBJ];
    __shared__ float red[4];
    int q = blockIdx.x;
    int t = threadIdx.x;
    if (t < N_OBJ) {
        float x = logits[q * N_OBJ + t];
        sp[t] = (x > 15.f) ? x : log1pf(expf(x));
    }
    __syncthreads();

    const int PT = 20;                 // 256*20 >= 4960
    float w[PT];
    float lmax = -1e30f;
#pragma unroll
    for (int k = 0; k < PT; k++) {
        int g = t * PT + k;
        float v = -1e30f;
        if (g < G_TOTAL) {
            int p = idxp[g];
            v = sp[p & 255] * sp[(p >> 8) & 255] * sp[(p >> 16) & 255];
        }
        w[k] = v;
        lmax = fmaxf(lmax, v);
    }
#pragma unroll
    for (int off = 32; off; off >>= 1) lmax = fmaxf(lmax, __shfl_down(lmax, off, 64));
    if ((t & 63) == 0) red[t >> 6] = lmax;
    __syncthreads();
    float wmax = fmaxf(fmaxf(red[0], red[1]), fmaxf(red[2], red[3]));

    float lsum = 0.f;
#pragma unroll
    for (int k = 0; k < PT; k++) {
        int g = t * PT + k;
        float e = (g < G_TOTAL) ? expf(w[k] - wmax) : 0.f;
        w[k] = e;
        lsum += e;
    }
#pragma unroll
    for (int off = 32; off; off >>= 1) lsum += __shfl_down(lsum, off, 64);
    __syncthreads();                    // everyone done reading red (max)
    if ((t & 63) == 0) red[t >> 6] = lsum;
    __syncthreads();
    float inv = 1.f / (red[0] + red[1] + red[2] + red[3]);

#pragma unroll
    for (int k = 0; k < PT; k++) {
        int g = t * PT + k;
        if (g < G_TOTAL) normw[(size_t)q * G_TOTAL + g] = f2bf(w[k] * inv);
    }
}

// ---------------- kernel B: rel_conv, one lane per (g,b), 16 filters in regs ------
// relT layout: [k=g][n=b*16+f], row stride 512, bf16
__global__ __launch_bounds__(256) void k_relconv(const float* __restrict__ inputs,
                                                 const float* __restrict__ filters,
                                                 const int* __restrict__ idxp,
                                                 unsigned short* __restrict__ relT) {
    int item = blockIdx.x * 256 + threadIdx.x;   // g*32 + b  (exact grid)
    int g = item >> 5;
    int b = item & 31;
    int p = idxp[g];
    int a0 = p & 255, a1 = (p >> 8) & 255, a2 = (p >> 16) & 255;

    float acc[N_FILT];
#pragma unroll
    for (int f = 0; f < N_FILT; f++) acc[f] = 0.f;

    const float* inb = inputs + (size_t)b * (N_OBJ * N_OBJ * REL_D);

#pragma unroll
    for (int i = 0; i < 3; i++) {
        int x = (i == 0) ? a0 : (i == 1) ? a1 : a2;
#pragma unroll
        for (int j = 0; j < 3; j++) {
            int y = (j == 0) ? a0 : (j == 1) ? a1 : a2;
            const float4* src = (const float4*)(inb + x * (N_OBJ * REL_D) + y * REL_D);
            float4 s0 = src[0], s1 = src[1], s2 = src[2], s3 = src[3];
            int pp = i * 3 + j;
#pragma unroll
            for (int f = 0; f < N_FILT; f++) {
                // wave-uniform address -> scalar loads through K$
                const float4* flt = (const float4*)(filters + f * (9 * REL_D) + pp * REL_D);
                float4 f0 = flt[0], f1 = flt[1], f2 = flt[2], f3 = flt[3];
                float d = s0.x * f0.x + s0.y * f0.y + s0.z * f0.z + s0.w * f0.w;
                d += s1.x * f1.x + s1.y * f1.y + s1.z * f1.z + s1.w * f1.w;
                d += s2.x * f2.x + s2.y * f2.y + s2.z * f2.z + s2.w * f2.w;
                d += s3.x * f3.x + s3.y * f3.y + s3.z * f3.z + s3.w * f3.w;
                acc[f] += d;
            }
        }
    }

    union { unsigned short u[16]; uint4 v[2]; } pack;
#pragma unroll
    for (int f = 0; f < N_FILT; f++) pack.u[f] = f2bf(acc[f]);
    uint4* dst = (uint4*)(relT + (size_t)g * 512 + b * 16);
    dst[0] = pack.v[0];
    dst[1] = pack.v[1];
}

// ---------------- kernel C: out = normw(512x4960) x relT(4960x512), bf16 MFMA -----
#define BM 64
#define BN 64
#define KB 32
#define KCHUNK 992   // 4960 / 5, = 31 * 32

__global__ __launch_bounds__(256) void k_gemm(const unsigned short* __restrict__ A,  // [512][4960]
                                              const unsigned short* __restrict__ Bm, // [4960][512]
                                              float* __restrict__ out) {             // [32][512][16]
    __shared__ unsigned short As[BM][KB];   // [m][k]
    __shared__ unsigned short Bs[BN][KB];   // [n][k], chunk-XOR swizzled
    int q0 = blockIdx.x * BM;
    int n0 = blockIdx.y * BN;
    int k0 = blockIdx.z * KCHUNK;
    int tid = threadIdx.x;
    int wave = tid >> 6, lane = tid & 63;
    int wm = wave & 1, wn = wave >> 1;      // 2x2 waves of 32x32
    int row16 = lane & 15, quad = lane >> 4;

    f32x4 acc[2][2] = {};

    // staging indices
    int am = tid >> 2, ac = (tid & 3) * 8;          // A: 64 rows x 4 chunks
    int bk = tid >> 3, bn = (tid & 7) * 8;          // B: 32 k-rows x 8 n-chunks

    for (int kk = 0; kk < KCHUNK; kk += KB) {
        // A stage: direct copy, [m][k]
        uint4 av = *(const uint4*)(A + (size_t)(q0 + am) * 4960 + (k0 + kk + ac));
        *(uint4*)&As[am][ac] = av;
        // B stage: transpose [k][n] -> [n][k] with chunk-XOR swizzle
        uint4 bv = *(const uint4*)(Bm + (size_t)(k0 + kk + bk) * 512 + (n0 + bn));
        const unsigned short* be = (const unsigned short*)&bv;
#pragma unroll
        for (int e = 0; e < 8; e++) {
            int n = bn + e;
            Bs[n][(bk & 7) + 8 * ((bk >> 3) ^ ((n >> 3) & 3))] = be[e];
        }
        __syncthreads();

        bf16x8 afr[2], bfr[2];
#pragma unroll
        for (int mi = 0; mi < 2; mi++)
            afr[mi] = *(const bf16x8*)&As[wm * 32 + mi * 16 + row16][quad * 8];
#pragma unroll
        for (int ni = 0; ni < 2; ni++) {
            int n = wn * 32 + ni * 16 + row16;
            bfr[ni] = *(const bf16x8*)&Bs[n][(quad ^ ((n >> 3) & 3)) * 8];
        }
#pragma unroll
        for (int mi = 0; mi < 2; mi++)
#pragma unroll
            for (int ni = 0; ni < 2; ni++)
                acc[mi][ni] = __builtin_amdgcn_mfma_f32_16x16x32_bf16(
                    afr[mi], bfr[ni], acc[mi][ni], 0, 0, 0);
        __syncthreads();
    }

    // epilogue: D row = quad*4+reg (=q), col = lane&15 (=n); scatter to out[b][q][r]
#pragma unroll
    for (int mi = 0; mi < 2; mi++)
#pragma unroll
        for (int ni = 0; ni < 2; ni++)
#pragma unroll
            for (int r = 0; r < 4; r++) {
                int q = q0 + wm * 32 + mi * 16 + quad * 4 + r;
                int n = n0 + wn * 32 + ni * 16 + row16;
                atomicAdd(out + (size_t)(n >> 4) * (NQ * REL_D) + q * REL_D + (n & 15),
                          acc[mi][ni][r]);
            }
}

extern "C" void kernel_launch(void* const* d_in, const int* in_sizes, int n_in,
                              void* d_out, int out_size, void* d_ws, size_t ws_size,
                              hipStream_t stream) {
    const float* inputs  = (const float*)d_in[0];   // (32,32,32,16)
    const float* logits  = (const float*)d_in[1];   // (512,32)
    const float* filters = (const float*)d_in[2];   // (16,3,3,16)
    float* out = (float*)d_out;                     // (32,512,16)

    char* ws = (char*)d_ws;
    int* idxp = (int*)ws;                                               // 19840 B
    unsigned short* normw = (unsigned short*)(ws + 32768);              // 512*4960*2
    unsigned short* relT  = (unsigned short*)(ws + 32768 + 5079040);    // 4960*512*2

    hipMemsetAsync(d_out, 0, (size_t)out_size * sizeof(float), stream);

    k_idx<<<(G_TOTAL + 255) / 256, 256, 0, stream>>>(idxp);
    k_normw<<<NQ, 256, 0, stream>>>(logits, idxp, normw);
    k_relconv<<<(G_TOTAL * BATCH) / 256, 256, 0, stream>>>(inputs, filters, idxp, relT);
    k_gemm<<<dim3(NQ / BM, 512 / BN, 5), 256, 0, stream>>>(normw, relT, out);
}

// Round 2
// 138.489 us; speedup vs baseline: 1.1294x; 1.1294x over previous
//
#include <hip/hip_runtime.h>
#include <hip/hip_bf16.h>

#define N_OBJ   32
#define G_TOTAL 4960      // C(32,3)
#define N_FILT  16
#define REL_D   16
#define BATCH   32
#define NQ      512

typedef __attribute__((ext_vector_type(8))) short bf16x8;
typedef __attribute__((ext_vector_type(4))) float f32x4;

static __device__ inline unsigned short f2bf(float x) {
    union { float f; unsigned int u; } v; v.f = x;
    unsigned int r = v.u + 0x7fffu + ((v.u >> 16) & 1u);   // RNE
    return (unsigned short)(r >> 16);
}
static __device__ inline float bfbits2f(unsigned int bits) {
    union { unsigned int u; float f; } v; v.u = bits; return v.f;
}
static __device__ inline void gload_lds16(const void* g, void* l) {
    __builtin_amdgcn_global_load_lds(
        (const __attribute__((address_space(1))) unsigned int*)g,
        (__attribute__((address_space(3))) unsigned int*)(unsigned int)(uintptr_t)l,
        16, 0, 0);
}

// ---------------- kernel 0: unrank lexicographic 3-combinations ----------------
__global__ void k_idx(int* __restrict__ idxp) {
    int g = blockIdx.x * 256 + threadIdx.x;
    if (g >= G_TOTAL) return;
    int rem = g, a = 0, b = 0;
    for (a = 0; a < N_OBJ - 2; a++) {
        int cnt = (N_OBJ - 1 - a) * (N_OBJ - 2 - a) / 2;
        if (rem < cnt) break;
        rem -= cnt;
    }
    for (b = a + 1; b < N_OBJ - 1; b++) {
        int cnt = N_OBJ - 1 - b;
        if (rem < cnt) break;
        rem -= cnt;
    }
    int c = b + 1 + rem;
    idxp[g] = a | (b << 8) | (c << 16);
}

// ---------------- kernel A: softplus -> product -> softmax -> bf16 ----------------
__global__ __launch_bounds__(256) void k_normw(const float* __restrict__ logits,
                                               const int* __restrict__ idxp,
                                               unsigned short* __restrict__ normw) {
    __shared__ float sp[N_OBJ];
    __shared__ float red[4];
    int q = blockIdx.x;
    int t = threadIdx.x;
    if (t < N_OBJ) {
        float x = logits[q * N_OBJ + t];
        sp[t] = (x > 15.f) ? x : log1pf(expf(x));
    }
    __syncthreads();

    const int PT = 20;                 // 256*20 >= 4960
    float w[PT];
    float lmax = -1e30f;
#pragma unroll
    for (int k = 0; k < PT; k++) {
        int g = t * PT + k;
        float v = -1e30f;
        if (g < G_TOTAL) {
            int p = idxp[g];
            v = sp[p & 255] * sp[(p >> 8) & 255] * sp[(p >> 16) & 255];
        }
        w[k] = v;
        lmax = fmaxf(lmax, v);
    }
#pragma unroll
    for (int off = 32; off; off >>= 1) lmax = fmaxf(lmax, __shfl_down(lmax, off, 64));
    if ((t & 63) == 0) red[t >> 6] = lmax;
    __syncthreads();
    float wmax = fmaxf(fmaxf(red[0], red[1]), fmaxf(red[2], red[3]));

    float lsum = 0.f;
#pragma unroll
    for (int k = 0; k < PT; k++) {
        int g = t * PT + k;
        float e = (g < G_TOTAL) ? expf(w[k] - wmax) : 0.f;
        w[k] = e;
        lsum += e;
    }
#pragma unroll
    for (int off = 32; off; off >>= 1) lsum += __shfl_down(lsum, off, 64);
    __syncthreads();
    if ((t & 63) == 0) red[t >> 6] = lsum;
    __syncthreads();
    float inv = 1.f / (red[0] + red[1] + red[2] + red[3]);

#pragma unroll
    for (int k = 0; k < PT; k++) {
        int g = t * PT + k;
        if (g < G_TOTAL) normw[(size_t)q * G_TOTAL + g] = f2bf(w[k] * inv);
    }
}

// ---------------- kernel B1: pair conv  D[x][y][p][b][f] = dot_d(inputs, filters) --
// grid (128, 9), 256 thr. p = blockIdx.y (wave-uniform). Coalesced row loads.
__global__ __launch_bounds__(256) void k_pairconv(const float* __restrict__ inputs,
                                                  const float* __restrict__ filters,
                                                  unsigned short* __restrict__ D) {
    __shared__ float flt[16 * 180];       // [f][p][d], (f,p) slice stride 20 floats
    int t = threadIdx.x;
    for (int i = t; i < 576; i += 256) {  // 2304 floats as float4
        int i4 = i * 4;
        int f = i4 / 144;
        int r = i4 - f * 144;
        *(float4*)&flt[f * 180 + (r >> 4) * 20 + (r & 15)] = *(const float4*)(filters + i4);
    }
    __syncthreads();

    int p = blockIdx.y;
    int row = blockIdx.x * 256 + t;       // row = b*1024 + x*32 + y
    int b = row >> 10, xy = row & 1023;
    const float4* src = (const float4*)(inputs + (size_t)row * 16);
    float4 s0 = src[0], s1 = src[1], s2 = src[2], s3 = src[3];

    unsigned short outv[16];
    const float* fb = &flt[p * 20];
#pragma unroll
    for (int f = 0; f < 16; f++) {
        float4 f0 = *(const float4*)(fb + f * 180);
        float4 f1 = *(const float4*)(fb + f * 180 + 4);
        float4 f2 = *(const float4*)(fb + f * 180 + 8);
        float4 f3 = *(const float4*)(fb + f * 180 + 12);
        float d = s0.x * f0.x + s0.y * f0.y + s0.z * f0.z + s0.w * f0.w;
        d += s1.x * f1.x + s1.y * f1.y + s1.z * f1.z + s1.w * f1.w;
        d += s2.x * f2.x + s2.y * f2.y + s2.z * f2.z + s2.w * f2.w;
        d += s3.x * f3.x + s3.y * f3.y + s3.z * f3.z + s3.w * f3.w;
        outv[f] = f2bf(d);
    }
    uint4* dst = (uint4*)(D + ((size_t)(xy * 9 + p)) * 512 + b * 16);
    dst[0] = ((uint4*)outv)[0];
    dst[1] = ((uint4*)outv)[1];
}

// ---------------- kernel B2: gather-sum 9 pairs -> relT[n=b*16+f][g]  (bf16) ------
// 310 blocks x 256 thr; block covers 16 g; thread covers n = {2t, 2t+1}.
__global__ __launch_bounds__(256) void k_gather(const unsigned short* __restrict__ D,
                                                const int* __restrict__ idxp,
                                                unsigned short* __restrict__ relT) {
    __shared__ int tri[16];
    int t = threadIdx.x;
    int g0 = blockIdx.x * 16;
    if (t < 16) tri[t] = idxp[g0 + t];
    __syncthreads();

    float s0[16], s1[16];
#pragma unroll 4
    for (int g = 0; g < 16; g++) {
        int pk = tri[g];
        int xs[3] = { pk & 255, (pk >> 8) & 255, (pk >> 16) & 255 };
        float x0 = 0.f, x1 = 0.f;
#pragma unroll
        for (int i = 0; i < 3; i++)
#pragma unroll
            for (int j = 0; j < 3; j++) {
                int xy = xs[i] * 32 + xs[j];
                unsigned int v = *(const unsigned int*)(D + (size_t)(xy * 9 + i * 3 + j) * 512 + t * 2);
                x0 += bfbits2f(v << 16);
                x1 += bfbits2f(v & 0xffff0000u);
            }
        s0[g] = x0; s1[g] = x1;
    }
    unsigned int pack0[8], pack1[8];
#pragma unroll
    for (int k = 0; k < 8; k++) {
        pack0[k] = f2bf(s0[2 * k]) | ((unsigned int)f2bf(s0[2 * k + 1]) << 16);
        pack1[k] = f2bf(s1[2 * k]) | ((unsigned int)f2bf(s1[2 * k + 1]) << 16);
    }
    uint4* d0 = (uint4*)(relT + (size_t)(2 * t) * G_TOTAL + g0);
    d0[0] = ((uint4*)pack0)[0];
    d0[1] = ((uint4*)pack0)[1];
    uint4* d1 = (uint4*)(relT + (size_t)(2 * t + 1) * G_TOTAL + g0);
    d1[0] = ((uint4*)pack1)[0];
    d1[1] = ((uint4*)pack1)[1];
}

// ---------------- kernel C: partials[z] = A(512x4960) x B^T, both [row][k] --------
#define KCH 992
#define NIT 31   // KCH / 32

__global__ __launch_bounds__(256) void k_gemm2(const unsigned short* __restrict__ A,
                                               const unsigned short* __restrict__ Bm,
                                               float* __restrict__ part) {
    __shared__ unsigned short As[2][64 * 32];
    __shared__ unsigned short Bs[2][64 * 32];
    int tid = threadIdx.x;
    int q0 = blockIdx.x * 64, n0 = blockIdx.y * 64, z = blockIdx.z;
    int k0 = z * KCH;
    int wave = tid >> 6, lane = tid & 63;
    int wm = wave & 1, wn = wave >> 1;
    int row16 = lane & 15, quad = lane >> 4;

    // staging: thread -> (row, slot); fetch global chunk slot^((row>>1)&3) so LDS
    // dest stays linear (tid*16) for global_load_lds while frag b128 reads are 2-way.
    int srow = tid >> 2;
    int schunk = (tid & 3) ^ ((srow >> 1) & 3);
    const unsigned short* ga = A + (size_t)(q0 + srow) * 4960 + k0 + schunk * 8;
    const unsigned short* gb = Bm + (size_t)(n0 + srow) * 4960 + k0 + schunk * 8;
    char* lA = (char*)&As[0][0] + tid * 16;
    char* lB = (char*)&Bs[0][0] + tid * 16;

    f32x4 acc[2][2] = {};
    int fchunk = (quad ^ ((row16 >> 1) & 3)) * 8;

    gload_lds16(ga, lA);
    gload_lds16(gb, lB);
    for (int it = 0; it < NIT; ++it) {
        __syncthreads();                       // staged loads for buf it&1 complete
        if (it + 1 < NIT) {
            int nb = (it + 1) & 1;
            gload_lds16(ga + (it + 1) * 32, lA + nb * 64 * 32 * 2);
            gload_lds16(gb + (it + 1) * 32, lB + nb * 64 * 32 * 2);
        }
        int buf = it & 1;
        bf16x8 afr[2], bfr[2];
#pragma unroll
        for (int mi = 0; mi < 2; mi++)
            afr[mi] = *(const bf16x8*)&As[buf][(wm * 32 + mi * 16 + row16) * 32 + fchunk];
#pragma unroll
        for (int ni = 0; ni < 2; ni++)
            bfr[ni] = *(const bf16x8*)&Bs[buf][(wn * 32 + ni * 16 + row16) * 32 + fchunk];
#pragma unroll
        for (int mi = 0; mi < 2; mi++)
#pragma unroll
            for (int ni = 0; ni < 2; ni++)
                acc[mi][ni] = __builtin_amdgcn_mfma_f32_16x16x32_bf16(
                    afr[mi], bfr[ni], acc[mi][ni], 0, 0, 0);
    }

    float* pz = part + (size_t)z * (NQ * 512);
#pragma unroll
    for (int mi = 0; mi < 2; mi++)
#pragma unroll
        for (int ni = 0; ni < 2; ni++)
#pragma unroll
            for (int r = 0; r < 4; r++) {
                int q = q0 + wm * 32 + mi * 16 + quad * 4 + r;
                int n = n0 + wn * 32 + ni * 16 + row16;
                pz[q * 512 + n] = acc[mi][ni][r];
            }
}

// ---------------- kernel D: reduce 5 split-K partials, remap to out[b][q][r] ------
__global__ __launch_bounds__(256) void k_reduce(const float* __restrict__ part,
                                                float* __restrict__ out) {
    int gid = blockIdx.x * 256 + threadIdx.x;   // 65536 threads
    int q = gid >> 7;
    int n = (gid & 127) * 4;
    float4 a = *(const float4*)(part + q * 512 + n);
#pragma unroll
    for (int zz = 1; zz < 5; zz++) {
        float4 bfour = *(const float4*)(part + (size_t)zz * (NQ * 512) + q * 512 + n);
        a.x += bfour.x; a.y += bfour.y; a.z += bfour.z; a.w += bfour.w;
    }
    *(float4*)(out + (size_t)(n >> 4) * (NQ * REL_D) + q * 16 + (n & 15)) = a;
}

extern "C" void kernel_launch(void* const* d_in, const int* in_sizes, int n_in,
                              void* d_out, int out_size, void* d_ws, size_t ws_size,
                              hipStream_t stream) {
    const float* inputs  = (const float*)d_in[0];   // (32,32,32,16)
    const float* logits  = (const float*)d_in[1];   // (512,32)
    const float* filters = (const float*)d_in[2];   // (16,3,3,16)
    float* out = (float*)d_out;                     // (32,512,16)

    char* ws = (char*)d_ws;
    int* idxp = (int*)ws;                                               // 19,840 B
    unsigned short* normw = (unsigned short*)(ws + 32768);              // 5,079,040 B
    unsigned short* relT  = (unsigned short*)(ws + 32768 + 5079040);    // 5,079,040 B
    unsigned short* D     = (unsigned short*)(ws + 10190848);           // 9,437,184 B
    float* part = (float*)(ws + 10190848);          // 5,242,880 B, reuses D (D dead)

    k_idx<<<(G_TOTAL + 255) / 256, 256, 0, stream>>>(idxp);
    k_normw<<<NQ, 256, 0, stream>>>(logits, idxp, normw);
    k_pairconv<<<dim3(128, 9), 256, 0, stream>>>(inputs, filters, D);
    k_gather<<<G_TOTAL / 16, 256, 0, stream>>>(D, idxp, relT);
    k_gemm2<<<dim3(8, 8, 5), 256, 0, stream>>>(normw, relT, part);
    k_reduce<<<NQ * 512 / 4 / 256, 256, 0, stream>>>(part, out);
}

// Round 3
// 112.000 us; speedup vs baseline: 1.3965x; 1.2365x over previous
//
#include <hip/hip_runtime.h>
#include <hip/hip_bf16.h>

#define N_OBJ   32
#define G_TOTAL 4960      // C(32,3)
#define N_FILT  16
#define REL_D   16
#define BATCH   32
#define NQ      512

typedef __attribute__((ext_vector_type(8))) short bf16x8;
typedef __attribute__((ext_vector_type(4))) float f32x4;

static __device__ inline unsigned short f2bf(float x) {
    union { float f; unsigned int u; } v; v.f = x;
    unsigned int r = v.u + 0x7fffu + ((v.u >> 16) & 1u);   // RNE
    return (unsigned short)(r >> 16);
}
static __device__ inline float bfbits2f(unsigned int bits) {
    union { unsigned int u; float f; } v; v.u = bits; return v.f;
}
static __device__ inline void gload_lds16(const void* g, void* l) {
    __builtin_amdgcn_global_load_lds(
        (const __attribute__((address_space(1))) unsigned int*)g,
        (__attribute__((address_space(3))) unsigned int*)(unsigned int)(uintptr_t)l,
        16, 0, 0);
}
// unrank lexicographic 3-combination of 32
static __device__ inline void unrank3(int g, int& a, int& b, int& c) {
    int rem = g;
    for (a = 0; a < 30; a++) { int cnt = ((31 - a) * (30 - a)) >> 1; if (rem < cnt) break; rem -= cnt; }
    for (b = a + 1; b < 31; b++) { if (rem < 31 - b) break; rem -= 31 - b; }
    c = b + 1 + rem;
}

// ================= L1: normw (blocks 0..511) + pairconv (512..1663) ==============
__global__ __launch_bounds__(256) void k_front(const float* __restrict__ logits,
                                               const float* __restrict__ inputs,
                                               const float* __restrict__ filters,
                                               unsigned short* __restrict__ normw,
                                               unsigned short* __restrict__ D) {
    __shared__ __align__(16) char smem[11648];
    int t = threadIdx.x;
    int role = blockIdx.x;

    if (role < NQ) {
        // ---------- normw: softplus -> triple product -> softmax -> bf16 ----------
        float* sp  = (float*)smem;                         // 32 floats
        float* red = (float*)(smem + 128);                 // 4 floats
        unsigned short* wrow = (unsigned short*)(smem + 144); // 4960 u16
        int q = role;
        if (t < N_OBJ) {
            float x = logits[q * N_OBJ + t];
            sp[t] = (x > 15.f) ? x : log1pf(expf(x));
        }
        __syncthreads();

        int g0 = t * 20;
        int aa, bb, cc;
        unrank3(g0, aa, bb, cc);

        float w[20];
        float lmax = -1e30f;
#pragma unroll
        for (int k = 0; k < 20; k++) {
            float v = -1e30f;
            if (g0 + k < G_TOTAL) v = sp[aa] * sp[bb] * sp[cc];
            w[k] = v;
            lmax = fmaxf(lmax, v);
            cc++;
            if (cc >= 32) { bb++; cc = bb + 1; if (cc >= 32) { aa++; bb = aa + 1; cc = bb + 1; } }
        }
#pragma unroll
        for (int off = 32; off; off >>= 1) lmax = fmaxf(lmax, __shfl_down(lmax, off, 64));
        if ((t & 63) == 0) red[t >> 6] = lmax;
        __syncthreads();
        float wmax = fmaxf(fmaxf(red[0], red[1]), fmaxf(red[2], red[3]));

        float lsum = 0.f;
#pragma unroll
        for (int k = 0; k < 20; k++) {
            float e = (g0 + k < G_TOTAL) ? expf(w[k] - wmax) : 0.f;
            w[k] = e;
            lsum += e;
        }
#pragma unroll
        for (int off = 32; off; off >>= 1) lsum += __shfl_down(lsum, off, 64);
        __syncthreads();
        if ((t & 63) == 0) red[t >> 6] = lsum;
        __syncthreads();
        float inv = 1.f / (red[0] + red[1] + red[2] + red[3]);

#pragma unroll
        for (int k = 0; k < 20; k++)
            if (g0 + k < G_TOTAL) wrow[g0 + k] = f2bf(w[k] * inv);
        __syncthreads();
        // coalesced row write: 4960 u16 = 620 uint4
        uint4* dstrow = (uint4*)(normw + (size_t)q * G_TOTAL);
        const uint4* srow = (const uint4*)wrow;
        for (int i = t; i < 620; i += 256) dstrow[i] = srow[i];
    } else {
        // ---------- pairconv: D[xy][p][b*16+f] = dot_d(inputs[b,x,y,:], filters[f,p,:])
        float* flt = (float*)smem;            // [f][p_pad] 16*180 floats
        int bid = role - NQ;                  // 0..1151
        int p = bid >> 7;                     // 0..8
        int xb = bid & 127;
        for (int i = t; i < 576; i += 256) {
            int i4 = i * 4;
            int f = i4 / 144;
            int r = i4 - f * 144;
            *(float4*)&flt[f * 180 + (r >> 4) * 20 + (r & 15)] = *(const float4*)(filters + i4);
        }
        __syncthreads();

        int row = xb * 256 + t;               // b*1024 + xy
        int b = row >> 10, xy = row & 1023;
        const float4* src = (const float4*)(inputs + (size_t)row * 16);
        float4 s0 = src[0], s1 = src[1], s2 = src[2], s3 = src[3];

        unsigned short outv[16];
        const float* fb = &flt[p * 20];
#pragma unroll
        for (int f = 0; f < 16; f++) {
            float4 f0 = *(const float4*)(fb + f * 180);
            float4 f1 = *(const float4*)(fb + f * 180 + 4);
            float4 f2 = *(const float4*)(fb + f * 180 + 8);
            float4 f3 = *(const float4*)(fb + f * 180 + 12);
            float d = s0.x * f0.x + s0.y * f0.y + s0.z * f0.z + s0.w * f0.w;
            d += s1.x * f1.x + s1.y * f1.y + s1.z * f1.z + s1.w * f1.w;
            d += s2.x * f2.x + s2.y * f2.y + s2.z * f2.z + s2.w * f2.w;
            d += s3.x * f3.x + s3.y * f3.y + s3.z * f3.z + s3.w * f3.w;
            outv[f] = f2bf(d);
        }
        uint4* dst = (uint4*)(D + ((size_t)(xy * 9 + p)) * 512 + b * 16);
        dst[0] = ((uint4*)outv)[0];
        dst[1] = ((uint4*)outv)[1];
    }
}

// ================= L2: gather (blocks 0..619, 8 g each) + zero-out (620..683) =====
__global__ __launch_bounds__(256) void k_mid(const unsigned short* __restrict__ D,
                                             unsigned short* __restrict__ relT,
                                             float* __restrict__ out) {
    __shared__ int tri[8];
    int t = threadIdx.x;
    int role = blockIdx.x;
    if (role >= 620) {
        int idx = (role - 620) * 256 + t;     // 16384 threads x 4 float4 = 1 MB
        float4 z = {0.f, 0.f, 0.f, 0.f};
        float4* o4 = (float4*)out;
#pragma unroll
        for (int j = 0; j < 4; j++) o4[idx + j * 16384] = z;
        return;
    }
    int g0 = role * 8;
    if (t < 8) {
        int a, b, c;
        unrank3(g0 + t, a, b, c);
        tri[t] = a | (b << 8) | (c << 16);
    }
    __syncthreads();

    float s0[8], s1[8];
#pragma unroll
    for (int g = 0; g < 8; g++) {
        int pk = tri[g];
        int xs[3] = { pk & 255, (pk >> 8) & 255, (pk >> 16) & 255 };
        float x0 = 0.f, x1 = 0.f;
#pragma unroll
        for (int i = 0; i < 3; i++)
#pragma unroll
            for (int j = 0; j < 3; j++) {
                int xy = xs[i] * 32 + xs[j];
                unsigned int v = *(const unsigned int*)(D + (size_t)(xy * 9 + i * 3 + j) * 512 + t * 2);
                x0 += bfbits2f(v << 16);
                x1 += bfbits2f(v & 0xffff0000u);
            }
        s0[g] = x0; s1[g] = x1;
    }
    unsigned int pack0[4], pack1[4];
#pragma unroll
    for (int k = 0; k < 4; k++) {
        pack0[k] = f2bf(s0[2 * k]) | ((unsigned int)f2bf(s0[2 * k + 1]) << 16);
        pack1[k] = f2bf(s1[2 * k]) | ((unsigned int)f2bf(s1[2 * k + 1]) << 16);
    }
    *(uint4*)(relT + (size_t)(2 * t) * G_TOTAL + g0)     = *(uint4*)pack0;
    *(uint4*)(relT + (size_t)(2 * t + 1) * G_TOTAL + g0) = *(uint4*)pack1;
}

// ================= L3: out += A(512x4960) x B^T, split-K=31, atomic epilogue ======
#define KCH 160
#define NIT 5    // KCH / 32

__global__ __launch_bounds__(256) void k_gemm3(const unsigned short* __restrict__ A,
                                               const unsigned short* __restrict__ Bm,
                                               float* __restrict__ out) {
    __shared__ unsigned short As[2][64 * 32];
    __shared__ unsigned short Bs[2][64 * 32];
    int tid = threadIdx.x;
    int q0 = blockIdx.x * 64, n0 = blockIdx.y * 64, z = blockIdx.z;
    int k0 = z * KCH;
    int wave = tid >> 6, lane = tid & 63;
    int wm = wave & 1, wn = wave >> 1;
    int row16 = lane & 15, quad = lane >> 4;

    int srow = tid >> 2;
    int schunk = (tid & 3) ^ ((srow >> 1) & 3);
    const unsigned short* ga = A + (size_t)(q0 + srow) * 4960 + k0 + schunk * 8;
    const unsigned short* gb = Bm + (size_t)(n0 + srow) * 4960 + k0 + schunk * 8;
    char* lA = (char*)&As[0][0] + tid * 16;
    char* lB = (char*)&Bs[0][0] + tid * 16;

    f32x4 acc[2][2] = {};
    int fchunk = (quad ^ ((row16 >> 1) & 3)) * 8;

    gload_lds16(ga, lA);
    gload_lds16(gb, lB);
    for (int it = 0; it < NIT; ++it) {
        __syncthreads();
        if (it + 1 < NIT) {
            int nb = (it + 1) & 1;
            gload_lds16(ga + (it + 1) * 32, lA + nb * 64 * 32 * 2);
            gload_lds16(gb + (it + 1) * 32, lB + nb * 64 * 32 * 2);
        }
        int buf = it & 1;
        bf16x8 afr[2], bfr[2];
#pragma unroll
        for (int mi = 0; mi < 2; mi++)
            afr[mi] = *(const bf16x8*)&As[buf][(wm * 32 + mi * 16 + row16) * 32 + fchunk];
#pragma unroll
        for (int ni = 0; ni < 2; ni++)
            bfr[ni] = *(const bf16x8*)&Bs[buf][(wn * 32 + ni * 16 + row16) * 32 + fchunk];
#pragma unroll
        for (int mi = 0; mi < 2; mi++)
#pragma unroll
            for (int ni = 0; ni < 2; ni++)
                acc[mi][ni] = __builtin_amdgcn_mfma_f32_16x16x32_bf16(
                    afr[mi], bfr[ni], acc[mi][ni], 0, 0, 0);
    }

#pragma unroll
    for (int mi = 0; mi < 2; mi++)
#pragma unroll
        for (int ni = 0; ni < 2; ni++)
#pragma unroll
            for (int r = 0; r < 4; r++) {
                int q = q0 + wm * 32 + mi * 16 + quad * 4 + r;
                int n = n0 + wn * 32 + ni * 16 + row16;
                atomicAdd(out + (size_t)(n >> 4) * (NQ * REL_D) + q * REL_D + (n & 15),
                          acc[mi][ni][r]);
            }
}

extern "C" void kernel_launch(void* const* d_in, const int* in_sizes, int n_in,
                              void* d_out, int out_size, void* d_ws, size_t ws_size,
                              hipStream_t stream) {
    const float* inputs  = (const float*)d_in[0];   // (32,32,32,16)
    const float* logits  = (const float*)d_in[1];   // (512,32)
    const float* filters = (const float*)d_in[2];   // (16,3,3,16)
    float* out = (float*)d_out;                     // (32,512,16)

    char* ws = (char*)d_ws;
    unsigned short* normw = (unsigned short*)ws;                 // 5,079,040 B
    unsigned short* D     = (unsigned short*)(ws + 5079040);     // 9,437,184 B
    unsigned short* relT  = (unsigned short*)(ws + 14516224);    // 5,079,040 B

    k_front<<<NQ + 1152, 256, 0, stream>>>(logits, inputs, filters, normw, D);
    k_mid<<<620 + 64, 256, 0, stream>>>(D, relT, out);
    k_gemm3<<<dim3(8, 8, 31), 256, 0, stream>>>(normw, relT, out);
}

// Round 4
// 94.912 us; speedup vs baseline: 1.6479x; 1.1800x over previous
//
#include <hip/hip_runtime.h>
#include <hip/hip_bf16.h>

#define N_OBJ   32
#define G_TOTAL 4960      // C(32,3)
#define GPAD    5120      // K padded to 32*160 for clean split-K
#define N_FILT  16
#define REL_D   16
#define BATCH   32
#define NQ      512
#define ZSPLIT  16
#define KCH     320       // GPAD / ZSPLIT
#define NIT     10        // KCH / 32

typedef __attribute__((ext_vector_type(8))) short bf16x8;
typedef __attribute__((ext_vector_type(4))) float f32x4;

static __device__ inline unsigned short f2bf(float x) {
    union { float f; unsigned int u; } v; v.f = x;
    unsigned int r = v.u + 0x7fffu + ((v.u >> 16) & 1u);   // RNE
    return (unsigned short)(r >> 16);
}
static __device__ inline float bfbits2f(unsigned int bits) {
    union { unsigned int u; float f; } v; v.u = bits; return v.f;
}
static __device__ inline void gload_lds16(const void* g, void* l) {
    __builtin_amdgcn_global_load_lds(
        (const __attribute__((address_space(1))) unsigned int*)g,
        (__attribute__((address_space(3))) unsigned int*)(unsigned int)(uintptr_t)l,
        16, 0, 0);
}
// unrank lexicographic 3-combination of 32
static __device__ inline void unrank3(int g, int& a, int& b, int& c) {
    int rem = g;
    for (a = 0; a < 30; a++) { int cnt = ((31 - a) * (30 - a)) >> 1; if (rem < cnt) break; rem -= cnt; }
    for (b = a + 1; b < 31; b++) { if (rem < 31 - b) break; rem -= 31 - b; }
    c = b + 1 + rem;
}

// ================= L1: normw (blocks 0..511) + pairconv (512..1663) ==============
__global__ __launch_bounds__(256) void k_front(const float* __restrict__ logits,
                                               const float* __restrict__ inputs,
                                               const float* __restrict__ filters,
                                               unsigned short* __restrict__ normw,
                                               unsigned short* __restrict__ D) {
    __shared__ __align__(16) char smem[11648];
    int t = threadIdx.x;
    int role = blockIdx.x;

    if (role < NQ) {
        // ---------- normw: softplus -> triple product -> softmax -> bf16, K-padded --
        float* sp  = (float*)smem;                            // 32 floats
        float* red = (float*)(smem + 128);                    // 4 floats
        unsigned short* wrow = (unsigned short*)(smem + 144); // 5120 u16
        int q = role;
        if (t < N_OBJ) {
            float x = logits[q * N_OBJ + t];
            sp[t] = (x > 15.f) ? x : log1pf(expf(x));
        }
        if (t < GPAD - G_TOTAL) wrow[G_TOTAL + t] = 0;        // zero the K-pad
        __syncthreads();

        int g0 = t * 20;
        int aa, bb, cc;
        unrank3(g0, aa, bb, cc);

        float w[20];
        float lmax = -1e30f;
#pragma unroll
        for (int k = 0; k < 20; k++) {
            float v = -1e30f;
            if (g0 + k < G_TOTAL) v = sp[aa] * sp[bb] * sp[cc];
            w[k] = v;
            lmax = fmaxf(lmax, v);
            cc++;
            if (cc >= 32) { bb++; cc = bb + 1; if (cc >= 32) { aa++; bb = aa + 1; cc = bb + 1; } }
        }
#pragma unroll
        for (int off = 32; off; off >>= 1) lmax = fmaxf(lmax, __shfl_down(lmax, off, 64));
        if ((t & 63) == 0) red[t >> 6] = lmax;
        __syncthreads();
        float wmax = fmaxf(fmaxf(red[0], red[1]), fmaxf(red[2], red[3]));

        float lsum = 0.f;
#pragma unroll
        for (int k = 0; k < 20; k++) {
            float e = (g0 + k < G_TOTAL) ? expf(w[k] - wmax) : 0.f;
            w[k] = e;
            lsum += e;
        }
#pragma unroll
        for (int off = 32; off; off >>= 1) lsum += __shfl_down(lsum, off, 64);
        __syncthreads();
        if ((t & 63) == 0) red[t >> 6] = lsum;
        __syncthreads();
        float inv = 1.f / (red[0] + red[1] + red[2] + red[3]);

#pragma unroll
        for (int k = 0; k < 20; k++)
            if (g0 + k < G_TOTAL) wrow[g0 + k] = f2bf(w[k] * inv);
        __syncthreads();
        // coalesced padded row write: 5120 u16 = 640 uint4
        uint4* dstrow = (uint4*)(normw + (size_t)q * GPAD);
        const uint4* srow = (const uint4*)wrow;
        for (int i = t; i < 640; i += 256) dstrow[i] = srow[i];
    } else {
        // ---------- pairconv: D[xy][p][b*16+f] = dot_d(inputs[b,x,y,:], filters[f,p,:])
        float* flt = (float*)smem;            // [f][p_pad] 16*180 floats
        int bid = role - NQ;                  // 0..1151
        int p = bid >> 7;                     // 0..8
        int xb = bid & 127;
        for (int i = t; i < 576; i += 256) {
            int i4 = i * 4;
            int f = i4 / 144;
            int r = i4 - f * 144;
            *(float4*)&flt[f * 180 + (r >> 4) * 20 + (r & 15)] = *(const float4*)(filters + i4);
        }
        __syncthreads();

        int row = xb * 256 + t;               // b*1024 + xy
        int b = row >> 10, xy = row & 1023;
        const float4* src = (const float4*)(inputs + (size_t)row * 16);
        float4 s0 = src[0], s1 = src[1], s2 = src[2], s3 = src[3];

        unsigned short outv[16];
        const float* fb = &flt[p * 20];
#pragma unroll
        for (int f = 0; f < 16; f++) {
            float4 f0 = *(const float4*)(fb + f * 180);
            float4 f1 = *(const float4*)(fb + f * 180 + 4);
            float4 f2 = *(const float4*)(fb + f * 180 + 8);
            float4 f3 = *(const float4*)(fb + f * 180 + 12);
            float d = s0.x * f0.x + s0.y * f0.y + s0.z * f0.z + s0.w * f0.w;
            d += s1.x * f1.x + s1.y * f1.y + s1.z * f1.z + s1.w * f1.w;
            d += s2.x * f2.x + s2.y * f2.y + s2.z * f2.z + s2.w * f2.w;
            d += s3.x * f3.x + s3.y * f3.y + s3.z * f3.z + s3.w * f3.w;
            outv[f] = f2bf(d);
        }
        uint4* dst = (uint4*)(D + ((size_t)(xy * 9 + p)) * 512 + b * 16);
        dst[0] = ((uint4*)outv)[0];
        dst[1] = ((uint4*)outv)[1];
    }
}

// ================= L2: gather 9 pairs -> relT[n=b*16+f][g]  (620 blocks, 8 g each) =
__global__ __launch_bounds__(256) void k_mid(const unsigned short* __restrict__ D,
                                             unsigned short* __restrict__ relT) {
    __shared__ int tri[8];
    int t = threadIdx.x;
    int g0 = blockIdx.x * 8;
    if (t < 8) {
        int a, b, c;
        unrank3(g0 + t, a, b, c);
        tri[t] = a | (b << 8) | (c << 16);
    }
    __syncthreads();

    float s0[8], s1[8];
#pragma unroll
    for (int g = 0; g < 8; g++) {
        int pk = tri[g];
        int xs[3] = { pk & 255, (pk >> 8) & 255, (pk >> 16) & 255 };
        float x0 = 0.f, x1 = 0.f;
#pragma unroll
        for (int i = 0; i < 3; i++)
#pragma unroll
            for (int j = 0; j < 3; j++) {
                int xy = xs[i] * 32 + xs[j];
                unsigned int v = *(const unsigned int*)(D + (size_t)(xy * 9 + i * 3 + j) * 512 + t * 2);
                x0 += bfbits2f(v << 16);
                x1 += bfbits2f(v & 0xffff0000u);
            }
        s0[g] = x0; s1[g] = x1;
    }
    unsigned int pack0[4], pack1[4];
#pragma unroll
    for (int k = 0; k < 4; k++) {
        pack0[k] = f2bf(s0[2 * k]) | ((unsigned int)f2bf(s0[2 * k + 1]) << 16);
        pack1[k] = f2bf(s1[2 * k]) | ((unsigned int)f2bf(s1[2 * k + 1]) << 16);
    }
    *(uint4*)(relT + (size_t)(2 * t) * GPAD + g0)     = *(uint4*)pack0;
    *(uint4*)(relT + (size_t)(2 * t + 1) * GPAD + g0) = *(uint4*)pack1;
}

// ================= L3: part[z] = A(512xGPAD) x B^T tile, no atomics ===============
__global__ __launch_bounds__(256) void k_gemm(const unsigned short* __restrict__ A,
                                              const unsigned short* __restrict__ Bm,
                                              float* __restrict__ part) {
    __shared__ __align__(16) unsigned short As[2][64 * 32];
    __shared__ __align__(16) unsigned short Bs[2][64 * 32];
    int tid = threadIdx.x;
    int q0 = blockIdx.x * 64, n0 = blockIdx.y * 64, z = blockIdx.z;
    int k0 = z * KCH;
    int wave = tid >> 6, lane = tid & 63;
    int wm = wave & 1, wn = wave >> 1;
    int row16 = lane & 15, quad = lane >> 4;

    int srow = tid >> 2;
    int schunk = (tid & 3) ^ ((srow >> 1) & 3);
    const unsigned short* ga = A + (size_t)(q0 + srow) * GPAD + k0 + schunk * 8;
    const unsigned short* gb = Bm + (size_t)(n0 + srow) * GPAD + k0 + schunk * 8;
    char* lA = (char*)&As[0][0] + tid * 16;
    char* lB = (char*)&Bs[0][0] + tid * 16;

    f32x4 acc[2][2] = {};
    int fchunk = (quad ^ ((row16 >> 1) & 3)) * 8;

    gload_lds16(ga, lA);
    gload_lds16(gb, lB);
    for (int it = 0; it < NIT; ++it) {
        __syncthreads();
        if (it + 1 < NIT) {
            int nb = (it + 1) & 1;
            gload_lds16(ga + (it + 1) * 32, lA + nb * 64 * 32 * 2);
            gload_lds16(gb + (it + 1) * 32, lB + nb * 64 * 32 * 2);
        }
        int buf = it & 1;
        bf16x8 afr[2], bfr[2];
#pragma unroll
        for (int mi = 0; mi < 2; mi++)
            afr[mi] = *(const bf16x8*)&As[buf][(wm * 32 + mi * 16 + row16) * 32 + fchunk];
#pragma unroll
        for (int ni = 0; ni < 2; ni++)
            bfr[ni] = *(const bf16x8*)&Bs[buf][(wn * 32 + ni * 16 + row16) * 32 + fchunk];
#pragma unroll
        for (int mi = 0; mi < 2; mi++)
#pragma unroll
            for (int ni = 0; ni < 2; ni++)
                acc[mi][ni] = __builtin_amdgcn_mfma_f32_16x16x32_bf16(
                    afr[mi], bfr[ni], acc[mi][ni], 0, 0, 0);
    }

    float* pz = part + (size_t)z * (NQ * 512);
#pragma unroll
    for (int mi = 0; mi < 2; mi++)
#pragma unroll
        for (int ni = 0; ni < 2; ni++)
#pragma unroll
            for (int r = 0; r < 4; r++) {
                int q = q0 + wm * 32 + mi * 16 + quad * 4 + r;
                int n = n0 + wn * 32 + ni * 16 + row16;
                pz[q * 512 + n] = acc[mi][ni][r];
            }
}

// ================= L4: reduce 16 split-K partials, remap to out[b][q][r] ==========
__global__ __launch_bounds__(256) void k_reduce(const float* __restrict__ part,
                                                float* __restrict__ out) {
    int gid = blockIdx.x * 256 + threadIdx.x;   // 65536 threads
    int q = gid >> 7;
    int n = (gid & 127) * 4;
    float4 a = *(const float4*)(part + q * 512 + n);
#pragma unroll
    for (int zz = 1; zz < ZSPLIT; zz++) {
        float4 b4 = *(const float4*)(part + (size_t)zz * (NQ * 512) + q * 512 + n);
        a.x += b4.x; a.y += b4.y; a.z += b4.z; a.w += b4.w;
    }
    *(float4*)(out + (size_t)(n >> 4) * (NQ * REL_D) + q * 16 + (n & 15)) = a;
}

extern "C" void kernel_launch(void* const* d_in, const int* in_sizes, int n_in,
                              void* d_out, int out_size, void* d_ws, size_t ws_size,
                              hipStream_t stream) {
    const float* inputs  = (const float*)d_in[0];   // (32,32,32,16)
    const float* logits  = (const float*)d_in[1];   // (512,32)
    const float* filters = (const float*)d_in[2];   // (16,3,3,16)
    float* out = (float*)d_out;                     // (32,512,16)

    char* ws = (char*)d_ws;
    unsigned short* normw = (unsigned short*)ws;                 //  5,242,880 B
    unsigned short* D     = (unsigned short*)(ws + 5242880);     //  9,437,184 B
    unsigned short* relT  = (unsigned short*)(ws + 14680064);    //  5,242,880 B
    float*          part  = (float*)(ws + 19922944);             // 16,777,216 B

    k_front<<<NQ + 1152, 256, 0, stream>>>(logits, inputs, filters, normw, D);
    k_mid<<<G_TOTAL / 8, 256, 0, stream>>>(D, relT);
    k_gemm<<<dim3(8, 8, ZSPLIT), 256, 0, stream>>>(normw, relT, part);
    k_reduce<<<NQ * 512 / 4 / 256, 256, 0, stream>>>(part, out);
}